// Round 17
// baseline (237.917 us; speedup 1.0000x reference)
//
#include <hip/hip_runtime.h>

#define NH   12
#define SEQ  1024
#define NB   8
#define DCAT 96
#define DV   80

typedef __attribute__((ext_vector_type(8))) short  bf16x8;
typedef __attribute__((ext_vector_type(4))) float  f32x4;
typedef __attribute__((ext_vector_type(4))) unsigned short u16x4;

static __device__ __forceinline__ unsigned short f2bf(float x) {
    unsigned int u = __float_as_uint(x);
    u += 0x7fffu + ((u >> 16) & 1u);   // RNE
    return (unsigned short)(u >> 16);
}
static __device__ __forceinline__ f32x4 fzero() {
    f32x4 z; z[0]=0.f; z[1]=0.f; z[2]=0.f; z[3]=0.f; return z;
}
static __device__ __forceinline__ unsigned int cvtpk(float lo, float hi) {
    unsigned int r;
    asm("v_cvt_pk_bf16_f32 %0, %1, %2" : "=v"(r) : "v"(lo), "v"(hi));
    return r;
}

#define GLDS16(gp, lp) __builtin_amdgcn_global_load_lds(                      \
    (const __attribute__((address_space(1))) void*)(gp),                      \
    (__attribute__((address_space(3))) void*)(lp), 16, 0, 0)

#define WAITV(nstr) asm volatile("s_waitcnt vmcnt(" nstr ")" ::: "memory")
#define SBARRIER() do {                                                       \
    __builtin_amdgcn_sched_barrier(0);                                        \
    asm volatile("" ::: "memory");                                            \
    __builtin_amdgcn_s_barrier();                                             \
    asm volatile("" ::: "memory");                                            \
    __builtin_amdgcn_sched_barrier(0);                                        \
} while (0)

// ---------------- fused f32 -> bf16 convert (all 8 tensors, 1 launch) ----------------
__global__ __launch_bounds__(256) void cvt_all(
    const float* __restrict__ hs, const float* __restrict__ lhs,
    const float* __restrict__ Wq, const float* __restrict__ Wk, const float* __restrict__ Wv,
    const float* __restrict__ Wlq, const float* __restrict__ Wlk, const float* __restrict__ Wlv,
    unsigned short* __restrict__ hid16, unsigned short* __restrict__ lay16,
    unsigned short* __restrict__ wqkv16, unsigned short* __restrict__ wl16)
{
    int i = blockIdx.x * 256 + threadIdx.x;
    const float* src; unsigned short* dst; int off;
    if      (i < 1572864) { src = hs;  dst = hid16;           off = i; }
    else if (i < 1966080) { src = lhs; dst = lay16;           off = i - 1572864; }
    else if (i < 2113536) { src = Wq;  dst = wqkv16;          off = i - 1966080; }
    else if (i < 2260992) { src = Wk;  dst = wqkv16 + 589824; off = i - 2113536; }
    else if (i < 2408448) { src = Wv;  dst = wqkv16 + 1179648;off = i - 2260992; }
    else if (i < 2417664) { src = Wlq; dst = wl16;            off = i - 2408448; }
    else if (i < 2426880) { src = Wlk; dst = wl16 + 36864;    off = i - 2417664; }
    else if (i < 2436096) { src = Wlv; dst = wl16 + 73728;    off = i - 2426880; }
    else return;
    f32x4 v = ((const f32x4*)src)[off];
    u16x4 o;
    o[0] = f2bf(v[0]); o[1] = f2bf(v[1]); o[2] = f2bf(v[2]); o[3] = f2bf(v[3]);
    ((u16x4*)dst)[off] = o;
}

// ---------------- pad fill: fold mask bias into K pad column, Q pad = 1 ----------------
// Kc[bh,s,80] = bf16((1-mask[b,s])*NEG)  (-inf if masked, 0 else)
// Qc[bh,s,80] = bf16(1.0)
// QK^T's third MFMA fragment (d=64..95) then adds the bias for free.
__global__ __launch_bounds__(256) void pad_fill(
    const float* __restrict__ mask,
    unsigned short* __restrict__ Qc, unsigned short* __restrict__ Kc)
{
    int i = blockIdx.x * 256 + threadIdx.x;   // 98304 = 96 bh x 1024 s
    if (i >= 98304) return;
    int bh = i >> 10, s = i & 1023;
    int b = bh / NH;
    float bias = (1.0f - mask[b * SEQ + s]) * -3.4028234663852886e38f;
    size_t idx = ((size_t)bh * SEQ + s) * DCAT + 80;
    Kc[idx] = f2bf(bias);
    Qc[idx] = 0x3F80;   // bf16 1.0
}

// ---------------- fused projection GEMM (both variants in ONE launch) ----------------
// blockIdx.y < 18: variant 0 (QKV, K=768, Ntot=2304); else variant 1 (LQKV).
// V written BLOCKED: VT[bh][kb=32][d=80][ko=32].
__global__ __launch_bounds__(256) void proj_gemm(
    const unsigned short* __restrict__ Ahid,
    const unsigned short* __restrict__ Alay,
    const unsigned short* __restrict__ Bwqkv,
    const unsigned short* __restrict__ Bwl,
    const float* __restrict__ bq, const float* __restrict__ bk, const float* __restrict__ bv,
    const float* __restrict__ blq, const float* __restrict__ blk_, const float* __restrict__ blv,
    unsigned short* __restrict__ Qc, unsigned short* __restrict__ Kc, unsigned short* __restrict__ VT)
{
    __shared__ __align__(16) unsigned short As[4096];   // [128][32]
    __shared__ __align__(16) unsigned short Bs[4096];   // [128][32]
    const int tid = threadIdx.x, w = tid >> 6, lane = tid & 63;
    const int g = lane >> 4, c = lane & 15;

    const int variant = (blockIdx.y < 18) ? 0 : 1;
    const unsigned short* A  = variant ? Alay : Ahid;
    const unsigned short* Bw = variant ? Bwl  : Bwqkv;
    const float* b0 = variant ? blq  : bq;
    const float* b1 = variant ? blk_ : bk;
    const float* b2 = variant ? blv  : bv;
    const int K    = variant ? 192 : 768;
    const int Ntot = variant ? 576 : 2304;
    const int m0 = blockIdx.x * 128;
    const int n0 = (variant ? (blockIdx.y - 18) : blockIdx.y) * 128;

    const int wr = w >> 1, wc = w & 1;
    const int srow = lane >> 2, scol = (lane & 3) * 8;

    f32x4 acc[4][4];
    #pragma unroll
    for (int m = 0; m < 4; m++)
        #pragma unroll
        for (int n = 0; n < 4; n++) acc[m][n] = fzero();

    const int ch0 = w * 2, ch1 = w * 2 + 1;
    const size_t arow0 = (size_t)(m0 + ch0 * 16 + srow) * K + scol;
    const size_t arow1 = (size_t)(m0 + ch1 * 16 + srow) * K + scol;
    int bn0 = n0 + ch0 * 16 + srow; if (bn0 >= Ntot) bn0 = Ntot - 1;
    int bn1 = n0 + ch1 * 16 + srow; if (bn1 >= Ntot) bn1 = Ntot - 1;
    const size_t brow0 = (size_t)bn0 * K + scol;
    const size_t brow1 = (size_t)bn1 * K + scol;

    for (int k0 = 0; k0 < K; k0 += 32) {
        __syncthreads();
        GLDS16(A  + arow0 + k0, As + ch0 * 512);
        GLDS16(A  + arow1 + k0, As + ch1 * 512);
        GLDS16(Bw + brow0 + k0, Bs + ch0 * 512);
        GLDS16(Bw + brow1 + k0, Bs + ch1 * 512);
        __syncthreads();
        bf16x8 af[4], bfr[4];
        #pragma unroll
        for (int m = 0; m < 4; m++) af[m]  = *(const bf16x8*)&As[(wr*64 + m*16 + c)*32 + g*8];
        #pragma unroll
        for (int n = 0; n < 4; n++) bfr[n] = *(const bf16x8*)&Bs[(wc*64 + n*16 + c)*32 + g*8];
        #pragma unroll
        for (int m = 0; m < 4; m++)
            #pragma unroll
            for (int n = 0; n < 4; n++)
                acc[m][n] = __builtin_amdgcn_mfma_f32_16x16x32_bf16(af[m], bfr[n], acc[m][n], 0, 0, 0);
    }

    const int b_ = m0 >> 10;
    #pragma unroll
    for (int nf = 0; nf < 4; nf++) {
        int n = n0 + wc * 64 + nf * 16 + c;
        if (n >= Ntot) continue;
        int seg, nn;
        if (variant == 0) { seg = (n >= 1536) ? 2 : ((n >= 768) ? 1 : 0); nn = n - seg * 768; }
        else              { seg = (n >= 384)  ? 2 : ((n >= 192) ? 1 : 0); nn = n - seg * 192; }
        const float* bp = (seg == 0) ? b0 : ((seg == 1) ? b1 : b2);
        float bv = bp[nn];
        float scale = (seg == 0) ? (variant ? 0.25f : 0.125f) : 1.0f;
        int h, d;
        if (variant == 0) { h = nn >> 6; d = nn & 63; }
        else              { h = nn >> 4; d = 64 + (nn & 15); }
        #pragma unroll
        for (int m = 0; m < 4; m++) {
            int row = m0 + wr * 64 + m * 16 + 4 * g;
            int s = row & 1023;
            if (seg < 2) {
                unsigned short* dst = (seg == 0) ? Qc : Kc;
                size_t base = (size_t)(b_ * NH + h) * SEQ;
                #pragma unroll
                for (int r = 0; r < 4; r++) {
                    dst[(base + s + r) * DCAT + d] = f2bf((acc[m][nf][r] + bv) * scale);
                    if (variant == 1)
                        dst[(base + s + r) * DCAT + d + 16] = 0;   // zero pad d=80..95
                }
            } else {
                u16x4 pk;
                #pragma unroll
                for (int r = 0; r < 4; r++) pk[r] = f2bf(acc[m][nf][r] + bv);
                int kb = s >> 5, ko = s & 31;
                *(u16x4*)&VT[(((size_t)(b_ * NH + h) * 32 + kb) * DV + d) * 32 + ko] = pk;
            }
        }
    }
}

// ---------------- fused attention v17: R13 structure, NO setprio, bias-in-K ----------------
// 768 blocks (XCD-swizzled), 4 waves x 32 q rows, swapped MFMA operands.
// Pass A (32-k unified K+V tiles, dbuf): QK^T (bias folded into pad col) ->
//   exp (unnormalized) -> row sums AND PV accumulate (deferred normalization).
// Pass B (64-k K-only LDS tiles, dbuf): QK^T -> exp*rinv -> probs store.
// vmcnt (in-order; body has no loads now):
//   pass A: WAITV "0" each tile (only GLDS outstanding)
//   pass B: WAITV "8" (8 probs stores from t-1 stay in flight), t=0: "0"
__global__ __launch_bounds__(256, 3) void attn_kernel(
    const unsigned short* __restrict__ Qc,   // [BH, SEQ, 96] bf16: q/8 | lq/4 | 1 | 0
    const unsigned short* __restrict__ Kc,   // [BH, SEQ, 96] bf16: k | lk | bias | 0
    const unsigned short* __restrict__ VT,   // [BH, 32, 80, 32] bf16 blocked
    float* __restrict__ ctx,                 // [NB, SEQ, 768]
    float* __restrict__ lctx,                // [NB, SEQ, 192]
    float* __restrict__ probs)               // [BH, SEQ, SEQ]
{
    __shared__ __align__(16) unsigned short Ks[2 * 6144];    // 24 KB dual-use
    __shared__ __align__(16) unsigned short pbuf[4][32][36];

    const int tid = threadIdx.x, w = tid >> 6, lane = tid & 63;
    const int g = lane >> 4, c = lane & 15;

    const int bid = blockIdx.x;
    const int xc = bid & 7, j = bid >> 3;     // j in 0..95
    const int bh = xc + 8 * (j >> 3);         // 0..95
    const int qt = j & 7;
    const int b = bh / NH, h = bh % NH;
    const int qrb = qt * 128 + w * 32;        // this wave's 32 q rows

    bf16x8 qa0, qa1, qa2, qb0, qb1, qb2;
    {
        const unsigned short* qr0 = &Qc[((size_t)bh * SEQ + qrb + c) * DCAT + g * 8];
        qa0 = *(const bf16x8*)(qr0);
        qa1 = *(const bf16x8*)(qr0 + 32);
        qa2 = *(const bf16x8*)(qr0 + 64);
        const unsigned short* qr1 = qr0 + 16 * DCAT;
        qb0 = *(const bf16x8*)(qr1);
        qb1 = *(const bf16x8*)(qr1 + 32);
        qb2 = *(const bf16x8*)(qr1 + 64);
    }
    const unsigned short* Kb = Kc + (size_t)bh * SEQ * DCAT;
    const unsigned short* Vb = VT + (size_t)bh * 32 * DV * 32;

    const int slot8 = (g ^ ((c >> 1) & 3)) * 8;   // K/V read chunk swizzle

    // ---- pass A staging geometry: 768 chunks = [K 384][V 320][pad 64] ----
    const unsigned short* gsrc[3]; int gstep[3];
    #pragma unroll
    for (int r = 0; r < 3; r++) {
        const int m = tid + 256 * r;
        if (m < 384) {          // K: [p:3][row:32][4ch], pre-swizzled source
            int p = m >> 7, row = (m >> 2) & 31, jj = m & 3;
            int jx = jj ^ ((row >> 1) & 3);
            gsrc[r]  = Kb + row * DCAT + p * 32 + jx * 8;
            gstep[r] = 32 * DCAT;                       // 3072 shorts / tile
        } else if (m < 704) {   // V: [df:5][cc:16][4ch], pre-swizzled source
            int mv = m - 384;
            int df = mv >> 6, cc = (mv >> 2) & 15, jj = mv & 3;
            int jx = jj ^ ((cc >> 1) & 3);
            gsrc[r]  = Vb + (df * 16 + cc) * 32 + jx * 8;
            gstep[r] = DV * 32;                         // 2560 shorts / tile
        } else {                // dummy pad
            gsrc[r]  = Vb;
            gstep[r] = 0;
        }
    }
    const int dub = w * 512;   // + r*2048 shorts, per-wave-uniform dest base

    // ---------------- pass A: unnormalized PV + row sums ----------------
    f32x4 cacc0[5], cacc1[5];
    #pragma unroll
    for (int nf = 0; nf < 5; nf++) { cacc0[nf] = fzero(); cacc1[nf] = fzero(); }
    float sm0 = 0.f, sm1 = 0.f;

    #pragma unroll
    for (int r = 0; r < 3; r++)
        GLDS16(gsrc[r], Ks + r * 2048 + dub);
    __builtin_amdgcn_sched_barrier(0);

    for (int t = 0; t < 32; t++) {
        const int buf = t & 1;
        WAITV("0");
        SBARRIER();
        if (t < 31) {
            #pragma unroll
            for (int r = 0; r < 3; r++)
                GLDS16(gsrc[r] + (t + 1) * gstep[r], Ks + (buf ^ 1) * 6144 + r * 2048 + dub);
            __builtin_amdgcn_sched_barrier(0);
        }

        #pragma unroll
        for (int ktl = 0; ktl < 2; ktl++) {
            const int rb = buf * 6144 + (ktl * 16 + c) * 32 + slot8;
            bf16x8 k0 = *(const bf16x8*)&Ks[rb];
            bf16x8 k1 = *(const bf16x8*)&Ks[rb + 1024];
            bf16x8 k2 = *(const bf16x8*)&Ks[rb + 2048];
            f32x4 a0 = __builtin_amdgcn_mfma_f32_16x16x32_bf16(k0, qa0, fzero(), 0, 0, 0);
            f32x4 a1 = __builtin_amdgcn_mfma_f32_16x16x32_bf16(k1, qa1, fzero(), 0, 0, 0);
            f32x4 a2 = __builtin_amdgcn_mfma_f32_16x16x32_bf16(k2, qa2, fzero(), 0, 0, 0);
            f32x4 b0 = __builtin_amdgcn_mfma_f32_16x16x32_bf16(k0, qb0, fzero(), 0, 0, 0);
            f32x4 b1 = __builtin_amdgcn_mfma_f32_16x16x32_bf16(k1, qb1, fzero(), 0, 0, 0);
            f32x4 b2 = __builtin_amdgcn_mfma_f32_16x16x32_bf16(k2, qb2, fzero(), 0, 0, 0);
            f32x4 e0, e1;
            #pragma unroll
            for (int r = 0; r < 4; r++) {
                e0[r] = __expf(a0[r] + a1[r] + a2[r]);
                e1[r] = __expf(b0[r] + b1[r] + b2[r]);
                sm0 += e0[r];
                sm1 += e1[r];
            }
            uint2 hh0, hh1;
            hh0.x = cvtpk(e0[0], e0[1]); hh0.y = cvtpk(e0[2], e0[3]);
            hh1.x = cvtpk(e1[0], e1[1]); hh1.y = cvtpk(e1[2], e1[3]);
            *(uint2*)&pbuf[w][c][ktl * 16 + 4 * g]      = hh0;
            *(uint2*)&pbuf[w][16 + c][ktl * 16 + 4 * g] = hh1;
        }
        // V from LDS, PV accumulate (unnormalized)
        const int vb0 = buf * 6144 + 3072 + c * 32 + slot8;
        bf16x8 vf0 = *(const bf16x8*)&Ks[vb0];
        bf16x8 vf1 = *(const bf16x8*)&Ks[vb0 + 512];
        bf16x8 vf2 = *(const bf16x8*)&Ks[vb0 + 1024];
        bf16x8 vf3 = *(const bf16x8*)&Ks[vb0 + 1536];
        bf16x8 vf4 = *(const bf16x8*)&Ks[vb0 + 2048];
        bf16x8 pa0 = *(const bf16x8*)&pbuf[w][c][g * 8];
        bf16x8 pa1 = *(const bf16x8*)&pbuf[w][16 + c][g * 8];
        cacc0[0] = __builtin_amdgcn_mfma_f32_16x16x32_bf16(pa0, vf0, cacc0[0], 0, 0, 0);
        cacc1[0] = __builtin_amdgcn_mfma_f32_16x16x32_bf16(pa1, vf0, cacc1[0], 0, 0, 0);
        cacc0[1] = __builtin_amdgcn_mfma_f32_16x16x32_bf16(pa0, vf1, cacc0[1], 0, 0, 0);
        cacc1[1] = __builtin_amdgcn_mfma_f32_16x16x32_bf16(pa1, vf1, cacc1[1], 0, 0, 0);
        cacc0[2] = __builtin_amdgcn_mfma_f32_16x16x32_bf16(pa0, vf2, cacc0[2], 0, 0, 0);
        cacc1[2] = __builtin_amdgcn_mfma_f32_16x16x32_bf16(pa1, vf2, cacc1[2], 0, 0, 0);
        cacc0[3] = __builtin_amdgcn_mfma_f32_16x16x32_bf16(pa0, vf3, cacc0[3], 0, 0, 0);
        cacc1[3] = __builtin_amdgcn_mfma_f32_16x16x32_bf16(pa1, vf3, cacc1[3], 0, 0, 0);
        cacc0[4] = __builtin_amdgcn_mfma_f32_16x16x32_bf16(pa0, vf4, cacc0[4], 0, 0, 0);
        cacc1[4] = __builtin_amdgcn_mfma_f32_16x16x32_bf16(pa1, vf4, cacc1[4], 0, 0, 0);
    }

    // ---- row sums -> rinv; transpose rinv to PV output layout via shfl ----
    sm0 += __shfl_xor(sm0, 16); sm0 += __shfl_xor(sm0, 32);
    sm1 += __shfl_xor(sm1, 16); sm1 += __shfl_xor(sm1, 32);
    const float rinv0 = 1.0f / fmaxf(sm0, 1e-38f);
    const float rinv1 = 1.0f / fmaxf(sm1, 1e-38f);

    float rl0[4], rl1[4];
    #pragma unroll
    for (int r = 0; r < 4; r++) {
        rl0[r] = __shfl(rinv0, 4 * g + r);   // lane 4g+r holds rinv for q=qrb+4g+r
        rl1[r] = __shfl(rinv1, 4 * g + r);
    }

    // ---- ctx/lctx epilogue (store-quiet window between passes) ----
    #pragma unroll
    for (int nf = 0; nf < 4; nf++)
        #pragma unroll
        for (int r = 0; r < 4; r++) {
            int q0 = qrb + 4 * g + r;
            ctx[((size_t)(b * SEQ + q0)) * 768 + h * 64 + nf * 16 + c] = cacc0[nf][r] * rl0[r];
            ctx[((size_t)(b * SEQ + q0 + 16)) * 768 + h * 64 + nf * 16 + c] = cacc1[nf][r] * rl1[r];
        }
    #pragma unroll
    for (int r = 0; r < 4; r++) {
        int q0 = qrb + 4 * g + r;
        lctx[((size_t)(b * SEQ + q0)) * 192 + h * 16 + c] = cacc0[4][r] * rl0[r];
        lctx[((size_t)(b * SEQ + q0 + 16)) * 192 + h * 16 + c] = cacc1[4][r] * rl1[r];
    }

    // ---------------- pass B: probs only (64-k K tiles) ----------------
    const int srow   = lane >> 2;
    const int schunk = (lane & 3) ^ ((lane >> 3) & 3);
    const int ssrcA  = (w * 16 + srow) * DCAT + schunk * 8;
    unsigned short* sdstA = &Ks[w * 512];

    const size_t prow0 = ((size_t)bh * SEQ + qrb + c) * SEQ;
    const size_t prow1 = prow0 + 16 * SEQ;

    SBARRIER();   // all waves done with pass-A LDS
    #pragma unroll
    for (int p = 0; p < 3; p++) GLDS16(Kb + ssrcA + p * 32, sdstA + p * 2048);
    __builtin_amdgcn_sched_barrier(0);

    for (int t = 0; t < 16; t++) {
        const int buf = t & 1;
        if (t == 0) WAITV("0");
        else        WAITV("8");
        SBARRIER();
        if (t < 15) {
            const unsigned short* src = Kb + (t + 1) * 6144 + ssrcA;
            unsigned short* dst = sdstA + (buf ^ 1) * 6144;
            #pragma unroll
            for (int p = 0; p < 3; p++) GLDS16(src + p * 32, dst + p * 2048);
            __builtin_amdgcn_sched_barrier(0);
        }
        #pragma unroll
        for (int ktl = 0; ktl < 4; ktl++) {
            const int rb = buf * 6144 + (ktl * 16 + c) * 32 + slot8;
            bf16x8 k0 = *(const bf16x8*)&Ks[rb];
            bf16x8 k1 = *(const bf16x8*)&Ks[rb + 2048];
            bf16x8 k2 = *(const bf16x8*)&Ks[rb + 4096];
            f32x4 a0 = __builtin_amdgcn_mfma_f32_16x16x32_bf16(k0, qa0, fzero(), 0, 0, 0);
            f32x4 a1 = __builtin_amdgcn_mfma_f32_16x16x32_bf16(k1, qa1, fzero(), 0, 0, 0);
            f32x4 a2 = __builtin_amdgcn_mfma_f32_16x16x32_bf16(k2, qa2, fzero(), 0, 0, 0);
            f32x4 b0 = __builtin_amdgcn_mfma_f32_16x16x32_bf16(k0, qb0, fzero(), 0, 0, 0);
            f32x4 b1 = __builtin_amdgcn_mfma_f32_16x16x32_bf16(k1, qb1, fzero(), 0, 0, 0);
            f32x4 b2 = __builtin_amdgcn_mfma_f32_16x16x32_bf16(k2, qb2, fzero(), 0, 0, 0);
            f32x4 p0, p1;
            #pragma unroll
            for (int r = 0; r < 4; r++) {
                p0[r] = __expf(a0[r] + a1[r] + a2[r]) * rinv0;
                p1[r] = __expf(b0[r] + b1[r] + b2[r]) * rinv1;
            }
            *(f32x4*)&probs[prow0 + (t * 64 + ktl * 16) + 4 * g] = p0;
            *(f32x4*)&probs[prow1 + (t * 64 + ktl * 16) + 4 * g] = p1;
        }
    }
}

// ---------------- host launch ----------------
extern "C" void kernel_launch(void* const* d_in, const int* in_sizes, int n_in,
                              void* d_out, int out_size, void* d_ws, size_t ws_size,
                              hipStream_t stream)
{
    const float* hs   = (const float*)d_in[0];
    const float* lhs  = (const float*)d_in[1];
    const float* mask = (const float*)d_in[2];
    const float* Wq   = (const float*)d_in[3];
    const float* bq   = (const float*)d_in[4];
    const float* Wk   = (const float*)d_in[5];
    const float* bk   = (const float*)d_in[6];
    const float* Wv   = (const float*)d_in[7];
    const float* bv   = (const float*)d_in[8];
    const float* Wlq  = (const float*)d_in[9];
    const float* blq  = (const float*)d_in[10];
    const float* Wlk  = (const float*)d_in[11];
    const float* blk_ = (const float*)d_in[12];
    const float* Wlv  = (const float*)d_in[13];
    const float* blv  = (const float*)d_in[14];

    float* out   = (float*)d_out;
    float* ctx   = out;
    float* lctx  = out + (size_t)NB * SEQ * 768;
    float* probs = out + (size_t)NB * SEQ * 768 + (size_t)NB * SEQ * 192;

    char* ws = (char*)d_ws;
    unsigned short* Qc     = (unsigned short*)(ws);                 // 18,874,368 B
    unsigned short* Kc     = (unsigned short*)(ws + 18874368);      // 18,874,368 B
    unsigned short* VT     = (unsigned short*)(ws + 37748736);      // 15,728,640 B
    unsigned short* hid16  = (unsigned short*)(ws + 53477376);      // 12,582,912 B
    unsigned short* lay16  = (unsigned short*)(ws + 66060288);      //  3,145,728 B
    unsigned short* wqkv16 = (unsigned short*)(ws + 69206016);      //  3,538,944 B
    unsigned short* wl16   = (unsigned short*)(ws + 72744960);      //    221,184 B

    cvt_all<<<dim3(9516), dim3(256), 0, stream>>>(hs, lhs, Wq, Wk, Wv, Wlq, Wlk, Wlv,
                                                  hid16, lay16, wqkv16, wl16);

    // both projection variants in one launch (y<18: QKV, y>=18: layout QKV)
    proj_gemm<<<dim3(64, 23), dim3(256), 0, stream>>>(hid16, lay16, wqkv16, wl16,
                                                      bq, bk, bv, blq, blk_, blv,
                                                      Qc, Kc, VT);

    // fold mask bias into K pad column (after proj writes the pads)
    pad_fill<<<dim3(384), dim3(256), 0, stream>>>(mask, Qc, Kc);

    attn_kernel<<<dim3(768), dim3(256), 0, stream>>>(Qc, Kc, VT, ctx, lctx, probs);
}

// Round 18
// 229.827 us; speedup vs baseline: 1.0352x; 1.0352x over previous
//
#include <hip/hip_runtime.h>

#define NH   12
#define SEQ  1024
#define NB   8
#define DCAT 96
#define DV   80

typedef __attribute__((ext_vector_type(8))) short  bf16x8;
typedef __attribute__((ext_vector_type(4))) float  f32x4;
typedef __attribute__((ext_vector_type(4))) unsigned short u16x4;

static __device__ __forceinline__ unsigned short f2bf(float x) {
    unsigned int u = __float_as_uint(x);
    u += 0x7fffu + ((u >> 16) & 1u);   // RNE
    return (unsigned short)(u >> 16);
}
static __device__ __forceinline__ f32x4 fzero() {
    f32x4 z; z[0]=0.f; z[1]=0.f; z[2]=0.f; z[3]=0.f; return z;
}
static __device__ __forceinline__ unsigned int cvtpk(float lo, float hi) {
    unsigned int r;
    asm("v_cvt_pk_bf16_f32 %0, %1, %2" : "=v"(r) : "v"(lo), "v"(hi));
    return r;
}

#define GLDS16(gp, lp) __builtin_amdgcn_global_load_lds(                      \
    (const __attribute__((address_space(1))) void*)(gp),                      \
    (__attribute__((address_space(3))) void*)(lp), 16, 0, 0)

#define WAITV(nstr) asm volatile("s_waitcnt vmcnt(" nstr ")" ::: "memory")
#define SBARRIER() do {                                                       \
    __builtin_amdgcn_sched_barrier(0);                                        \
    asm volatile("" ::: "memory");                                            \
    __builtin_amdgcn_s_barrier();                                             \
    asm volatile("" ::: "memory");                                            \
    __builtin_amdgcn_sched_barrier(0);                                        \
} while (0)

// ---------------- fused f32 -> bf16 convert (all 8 tensors, 1 launch) ----------------
__global__ __launch_bounds__(256) void cvt_all(
    const float* __restrict__ hs, const float* __restrict__ lhs,
    const float* __restrict__ Wq, const float* __restrict__ Wk, const float* __restrict__ Wv,
    const float* __restrict__ Wlq, const float* __restrict__ Wlk, const float* __restrict__ Wlv,
    unsigned short* __restrict__ hid16, unsigned short* __restrict__ lay16,
    unsigned short* __restrict__ wqkv16, unsigned short* __restrict__ wl16)
{
    int i = blockIdx.x * 256 + threadIdx.x;
    const float* src; unsigned short* dst; int off;
    if      (i < 1572864) { src = hs;  dst = hid16;           off = i; }
    else if (i < 1966080) { src = lhs; dst = lay16;           off = i - 1572864; }
    else if (i < 2113536) { src = Wq;  dst = wqkv16;          off = i - 1966080; }
    else if (i < 2260992) { src = Wk;  dst = wqkv16 + 589824; off = i - 2113536; }
    else if (i < 2408448) { src = Wv;  dst = wqkv16 + 1179648;off = i - 2260992; }
    else if (i < 2417664) { src = Wlq; dst = wl16;            off = i - 2408448; }
    else if (i < 2426880) { src = Wlk; dst = wl16 + 36864;    off = i - 2417664; }
    else if (i < 2436096) { src = Wlv; dst = wl16 + 73728;    off = i - 2426880; }
    else return;
    f32x4 v = ((const f32x4*)src)[off];
    u16x4 o;
    o[0] = f2bf(v[0]); o[1] = f2bf(v[1]); o[2] = f2bf(v[2]); o[3] = f2bf(v[3]);
    ((u16x4*)dst)[off] = o;
}

// ---------------- pad fill: fold mask bias into K pad column, Q pad = 1 ----------------
__global__ __launch_bounds__(256) void pad_fill(
    const float* __restrict__ mask,
    unsigned short* __restrict__ Qc, unsigned short* __restrict__ Kc)
{
    int i = blockIdx.x * 256 + threadIdx.x;   // 98304 = 96 bh x 1024 s
    if (i >= 98304) return;
    int bh = i >> 10, s = i & 1023;
    int b = bh / NH;
    float bias = (1.0f - mask[b * SEQ + s]) * -3.4028234663852886e38f;
    size_t idx = ((size_t)bh * SEQ + s) * DCAT + 80;
    Kc[idx] = f2bf(bias);
    Qc[idx] = 0x3F80;   // bf16 1.0
}

// ---------------- fused projection GEMM (both variants in ONE launch) ----------------
__global__ __launch_bounds__(256) void proj_gemm(
    const unsigned short* __restrict__ Ahid,
    const unsigned short* __restrict__ Alay,
    const unsigned short* __restrict__ Bwqkv,
    const unsigned short* __restrict__ Bwl,
    const float* __restrict__ bq, const float* __restrict__ bk, const float* __restrict__ bv,
    const float* __restrict__ blq, const float* __restrict__ blk_, const float* __restrict__ blv,
    unsigned short* __restrict__ Qc, unsigned short* __restrict__ Kc, unsigned short* __restrict__ VT)
{
    __shared__ __align__(16) unsigned short As[4096];   // [128][32]
    __shared__ __align__(16) unsigned short Bs[4096];   // [128][32]
    const int tid = threadIdx.x, w = tid >> 6, lane = tid & 63;
    const int g = lane >> 4, c = lane & 15;

    const int variant = (blockIdx.y < 18) ? 0 : 1;
    const unsigned short* A  = variant ? Alay : Ahid;
    const unsigned short* Bw = variant ? Bwl  : Bwqkv;
    const float* b0 = variant ? blq  : bq;
    const float* b1 = variant ? blk_ : bk;
    const float* b2 = variant ? blv  : bv;
    const int K    = variant ? 192 : 768;
    const int Ntot = variant ? 576 : 2304;
    const int m0 = blockIdx.x * 128;
    const int n0 = (variant ? (blockIdx.y - 18) : blockIdx.y) * 128;

    const int wr = w >> 1, wc = w & 1;
    const int srow = lane >> 2, scol = (lane & 3) * 8;

    f32x4 acc[4][4];
    #pragma unroll
    for (int m = 0; m < 4; m++)
        #pragma unroll
        for (int n = 0; n < 4; n++) acc[m][n] = fzero();

    const int ch0 = w * 2, ch1 = w * 2 + 1;
    const size_t arow0 = (size_t)(m0 + ch0 * 16 + srow) * K + scol;
    const size_t arow1 = (size_t)(m0 + ch1 * 16 + srow) * K + scol;
    int bn0 = n0 + ch0 * 16 + srow; if (bn0 >= Ntot) bn0 = Ntot - 1;
    int bn1 = n0 + ch1 * 16 + srow; if (bn1 >= Ntot) bn1 = Ntot - 1;
    const size_t brow0 = (size_t)bn0 * K + scol;
    const size_t brow1 = (size_t)bn1 * K + scol;

    for (int k0 = 0; k0 < K; k0 += 32) {
        __syncthreads();
        GLDS16(A  + arow0 + k0, As + ch0 * 512);
        GLDS16(A  + arow1 + k0, As + ch1 * 512);
        GLDS16(Bw + brow0 + k0, Bs + ch0 * 512);
        GLDS16(Bw + brow1 + k0, Bs + ch1 * 512);
        __syncthreads();
        bf16x8 af[4], bfr[4];
        #pragma unroll
        for (int m = 0; m < 4; m++) af[m]  = *(const bf16x8*)&As[(wr*64 + m*16 + c)*32 + g*8];
        #pragma unroll
        for (int n = 0; n < 4; n++) bfr[n] = *(const bf16x8*)&Bs[(wc*64 + n*16 + c)*32 + g*8];
        #pragma unroll
        for (int m = 0; m < 4; m++)
            #pragma unroll
            for (int n = 0; n < 4; n++)
                acc[m][n] = __builtin_amdgcn_mfma_f32_16x16x32_bf16(af[m], bfr[n], acc[m][n], 0, 0, 0);
    }

    const int b_ = m0 >> 10;
    #pragma unroll
    for (int nf = 0; nf < 4; nf++) {
        int n = n0 + wc * 64 + nf * 16 + c;
        if (n >= Ntot) continue;
        int seg, nn;
        if (variant == 0) { seg = (n >= 1536) ? 2 : ((n >= 768) ? 1 : 0); nn = n - seg * 768; }
        else              { seg = (n >= 384)  ? 2 : ((n >= 192) ? 1 : 0); nn = n - seg * 192; }
        const float* bp = (seg == 0) ? b0 : ((seg == 1) ? b1 : b2);
        float bv = bp[nn];
        float scale = (seg == 0) ? (variant ? 0.25f : 0.125f) : 1.0f;
        int h, d;
        if (variant == 0) { h = nn >> 6; d = nn & 63; }
        else              { h = nn >> 4; d = 64 + (nn & 15); }
        #pragma unroll
        for (int m = 0; m < 4; m++) {
            int row = m0 + wr * 64 + m * 16 + 4 * g;
            int s = row & 1023;
            if (seg < 2) {
                unsigned short* dst = (seg == 0) ? Qc : Kc;
                size_t base = (size_t)(b_ * NH + h) * SEQ;
                #pragma unroll
                for (int r = 0; r < 4; r++) {
                    dst[(base + s + r) * DCAT + d] = f2bf((acc[m][nf][r] + bv) * scale);
                    if (variant == 1)
                        dst[(base + s + r) * DCAT + d + 16] = 0;   // zero pad d=80..95
                }
            } else {
                u16x4 pk;
                #pragma unroll
                for (int r = 0; r < 4; r++) pk[r] = f2bf(acc[m][nf][r] + bv);
                int kb = s >> 5, ko = s & 31;
                *(u16x4*)&VT[(((size_t)(b_ * NH + h) * 32 + kb) * DV + d) * 32 + ko] = pk;
            }
        }
    }
}

// ---------------- attn_a: pass A only (PV + row sums), writes ctx/lctx/rinv ----------------
// 768 blocks (XCD-swizzled), 4 waves x 32 q rows, swapped MFMA, bias-in-K.
__global__ __launch_bounds__(256, 3) void attn_a(
    const unsigned short* __restrict__ Qc,   // [BH, SEQ, 96] bf16: q/8 | lq/4 | 1 | 0
    const unsigned short* __restrict__ Kc,   // [BH, SEQ, 96] bf16: k | lk | bias | 0
    const unsigned short* __restrict__ VT,   // [BH, 32, 80, 32] bf16 blocked
    float* __restrict__ ctx,                 // [NB, SEQ, 768]
    float* __restrict__ lctx,                // [NB, SEQ, 192]
    float* __restrict__ rinvbuf)             // [BH, SEQ]
{
    __shared__ __align__(16) unsigned short Ks[2 * 6144];    // 24 KB dual-use
    __shared__ __align__(16) unsigned short pbuf[4][32][36];

    const int tid = threadIdx.x, w = tid >> 6, lane = tid & 63;
    const int g = lane >> 4, c = lane & 15;

    const int bid = blockIdx.x;
    const int xc = bid & 7, j = bid >> 3;     // j in 0..95
    const int bh = xc + 8 * (j >> 3);         // 0..95
    const int qt = j & 7;
    const int b = bh / NH, h = bh % NH;
    const int qrb = qt * 128 + w * 32;        // this wave's 32 q rows

    bf16x8 qa0, qa1, qa2, qb0, qb1, qb2;
    {
        const unsigned short* qr0 = &Qc[((size_t)bh * SEQ + qrb + c) * DCAT + g * 8];
        qa0 = *(const bf16x8*)(qr0);
        qa1 = *(const bf16x8*)(qr0 + 32);
        qa2 = *(const bf16x8*)(qr0 + 64);
        const unsigned short* qr1 = qr0 + 16 * DCAT;
        qb0 = *(const bf16x8*)(qr1);
        qb1 = *(const bf16x8*)(qr1 + 32);
        qb2 = *(const bf16x8*)(qr1 + 64);
    }
    const unsigned short* Kb = Kc + (size_t)bh * SEQ * DCAT;
    const unsigned short* Vb = VT + (size_t)bh * 32 * DV * 32;

    const int slot8 = (g ^ ((c >> 1) & 3)) * 8;   // K/V read chunk swizzle

    // staging geometry: 768 chunks = [K 384][V 320][pad 64]
    const unsigned short* gsrc[3]; int gstep[3];
    #pragma unroll
    for (int r = 0; r < 3; r++) {
        const int m = tid + 256 * r;
        if (m < 384) {
            int p = m >> 7, row = (m >> 2) & 31, jj = m & 3;
            int jx = jj ^ ((row >> 1) & 3);
            gsrc[r]  = Kb + row * DCAT + p * 32 + jx * 8;
            gstep[r] = 32 * DCAT;
        } else if (m < 704) {
            int mv = m - 384;
            int df = mv >> 6, cc = (mv >> 2) & 15, jj = mv & 3;
            int jx = jj ^ ((cc >> 1) & 3);
            gsrc[r]  = Vb + (df * 16 + cc) * 32 + jx * 8;
            gstep[r] = DV * 32;
        } else {
            gsrc[r]  = Vb;
            gstep[r] = 0;
        }
    }
    const int dub = w * 512;

    f32x4 cacc0[5], cacc1[5];
    #pragma unroll
    for (int nf = 0; nf < 5; nf++) { cacc0[nf] = fzero(); cacc1[nf] = fzero(); }
    float sm0 = 0.f, sm1 = 0.f;

    #pragma unroll
    for (int r = 0; r < 3; r++)
        GLDS16(gsrc[r], Ks + r * 2048 + dub);
    __builtin_amdgcn_sched_barrier(0);

    for (int t = 0; t < 32; t++) {
        const int buf = t & 1;
        WAITV("0");
        SBARRIER();
        if (t < 31) {
            #pragma unroll
            for (int r = 0; r < 3; r++)
                GLDS16(gsrc[r] + (t + 1) * gstep[r], Ks + (buf ^ 1) * 6144 + r * 2048 + dub);
            __builtin_amdgcn_sched_barrier(0);
        }

        #pragma unroll
        for (int ktl = 0; ktl < 2; ktl++) {
            const int rb = buf * 6144 + (ktl * 16 + c) * 32 + slot8;
            bf16x8 k0 = *(const bf16x8*)&Ks[rb];
            bf16x8 k1 = *(const bf16x8*)&Ks[rb + 1024];
            bf16x8 k2 = *(const bf16x8*)&Ks[rb + 2048];
            f32x4 a0 = __builtin_amdgcn_mfma_f32_16x16x32_bf16(k0, qa0, fzero(), 0, 0, 0);
            f32x4 a1 = __builtin_amdgcn_mfma_f32_16x16x32_bf16(k1, qa1, fzero(), 0, 0, 0);
            f32x4 a2 = __builtin_amdgcn_mfma_f32_16x16x32_bf16(k2, qa2, fzero(), 0, 0, 0);
            f32x4 b0 = __builtin_amdgcn_mfma_f32_16x16x32_bf16(k0, qb0, fzero(), 0, 0, 0);
            f32x4 b1 = __builtin_amdgcn_mfma_f32_16x16x32_bf16(k1, qb1, fzero(), 0, 0, 0);
            f32x4 b2 = __builtin_amdgcn_mfma_f32_16x16x32_bf16(k2, qb2, fzero(), 0, 0, 0);
            f32x4 e0, e1;
            #pragma unroll
            for (int r = 0; r < 4; r++) {
                e0[r] = __expf(a0[r] + a1[r] + a2[r]);
                e1[r] = __expf(b0[r] + b1[r] + b2[r]);
                sm0 += e0[r];
                sm1 += e1[r];
            }
            uint2 hh0, hh1;
            hh0.x = cvtpk(e0[0], e0[1]); hh0.y = cvtpk(e0[2], e0[3]);
            hh1.x = cvtpk(e1[0], e1[1]); hh1.y = cvtpk(e1[2], e1[3]);
            *(uint2*)&pbuf[w][c][ktl * 16 + 4 * g]      = hh0;
            *(uint2*)&pbuf[w][16 + c][ktl * 16 + 4 * g] = hh1;
        }
        const int vb0 = buf * 6144 + 3072 + c * 32 + slot8;
        bf16x8 vf0 = *(const bf16x8*)&Ks[vb0];
        bf16x8 vf1 = *(const bf16x8*)&Ks[vb0 + 512];
        bf16x8 vf2 = *(const bf16x8*)&Ks[vb0 + 1024];
        bf16x8 vf3 = *(const bf16x8*)&Ks[vb0 + 1536];
        bf16x8 vf4 = *(const bf16x8*)&Ks[vb0 + 2048];
        bf16x8 pa0 = *(const bf16x8*)&pbuf[w][c][g * 8];
        bf16x8 pa1 = *(const bf16x8*)&pbuf[w][16 + c][g * 8];
        cacc0[0] = __builtin_amdgcn_mfma_f32_16x16x32_bf16(pa0, vf0, cacc0[0], 0, 0, 0);
        cacc1[0] = __builtin_amdgcn_mfma_f32_16x16x32_bf16(pa1, vf0, cacc1[0], 0, 0, 0);
        cacc0[1] = __builtin_amdgcn_mfma_f32_16x16x32_bf16(pa0, vf1, cacc0[1], 0, 0, 0);
        cacc1[1] = __builtin_amdgcn_mfma_f32_16x16x32_bf16(pa1, vf1, cacc1[1], 0, 0, 0);
        cacc0[2] = __builtin_amdgcn_mfma_f32_16x16x32_bf16(pa0, vf2, cacc0[2], 0, 0, 0);
        cacc1[2] = __builtin_amdgcn_mfma_f32_16x16x32_bf16(pa1, vf2, cacc1[2], 0, 0, 0);
        cacc0[3] = __builtin_amdgcn_mfma_f32_16x16x32_bf16(pa0, vf3, cacc0[3], 0, 0, 0);
        cacc1[3] = __builtin_amdgcn_mfma_f32_16x16x32_bf16(pa1, vf3, cacc1[3], 0, 0, 0);
        cacc0[4] = __builtin_amdgcn_mfma_f32_16x16x32_bf16(pa0, vf4, cacc0[4], 0, 0, 0);
        cacc1[4] = __builtin_amdgcn_mfma_f32_16x16x32_bf16(pa1, vf4, cacc1[4], 0, 0, 0);
    }

    // ---- row sums -> rinv; store rinv; normalize + write ctx/lctx ----
    sm0 += __shfl_xor(sm0, 16); sm0 += __shfl_xor(sm0, 32);
    sm1 += __shfl_xor(sm1, 16); sm1 += __shfl_xor(sm1, 32);
    const float rinv0 = 1.0f / fmaxf(sm0, 1e-38f);
    const float rinv1 = 1.0f / fmaxf(sm1, 1e-38f);

    if (g == 0) {
        rinvbuf[(size_t)bh * SEQ + qrb + c]      = rinv0;
        rinvbuf[(size_t)bh * SEQ + qrb + 16 + c] = rinv1;
    }

    float rl0[4], rl1[4];
    #pragma unroll
    for (int r = 0; r < 4; r++) {
        rl0[r] = __shfl(rinv0, 4 * g + r);
        rl1[r] = __shfl(rinv1, 4 * g + r);
    }

    #pragma unroll
    for (int nf = 0; nf < 4; nf++)
        #pragma unroll
        for (int r = 0; r < 4; r++) {
            int q0 = qrb + 4 * g + r;
            ctx[((size_t)(b * SEQ + q0)) * 768 + h * 64 + nf * 16 + c] = cacc0[nf][r] * rl0[r];
            ctx[((size_t)(b * SEQ + q0 + 16)) * 768 + h * 64 + nf * 16 + c] = cacc1[nf][r] * rl1[r];
        }
    #pragma unroll
    for (int r = 0; r < 4; r++) {
        int q0 = qrb + 4 * g + r;
        lctx[((size_t)(b * SEQ + q0)) * 192 + h * 16 + c] = cacc0[4][r] * rl0[r];
        lctx[((size_t)(b * SEQ + q0 + 16)) * 192 + h * 16 + c] = cacc1[4][r] * rl1[r];
    }
}

// ---------------- attn_b: probs-only streaming kernel, k-split for occupancy ----------------
// grid 1536 (96 bh x 8 qt x 2 k-halves, XCD-swizzled). 4 waves x 32 q rows,
// each block covers 512 k columns (8 x 64-k LDS tiles, dbuf). LDS 24 KB,
// low VGPR -> 4+ blocks/CU: 2x the waves of the monolithic version for the
// store-bound phase.
__global__ __launch_bounds__(256, 4) void attn_b(
    const unsigned short* __restrict__ Qc,
    const unsigned short* __restrict__ Kc,
    const float* __restrict__ rinvbuf,       // [BH, SEQ]
    float* __restrict__ probs)               // [BH, SEQ, SEQ]
{
    __shared__ __align__(16) unsigned short Ks[2 * 6144];    // 24 KB

    const int tid = threadIdx.x, w = tid >> 6, lane = tid & 63;
    const int g = lane >> 4, c = lane & 15;

    const int bid = blockIdx.x;
    const int xc = bid & 7, j = bid >> 3;     // j in 0..191
    const int bh = xc + 8 * (j >> 4);         // 0..95
    const int sub = j & 15;
    const int qt = sub >> 1, kh = sub & 1;
    const int qrb = qt * 128 + w * 32;

    bf16x8 qa0, qa1, qa2, qb0, qb1, qb2;
    {
        const unsigned short* qr0 = &Qc[((size_t)bh * SEQ + qrb + c) * DCAT + g * 8];
        qa0 = *(const bf16x8*)(qr0);
        qa1 = *(const bf16x8*)(qr0 + 32);
        qa2 = *(const bf16x8*)(qr0 + 64);
        const unsigned short* qr1 = qr0 + 16 * DCAT;
        qb0 = *(const bf16x8*)(qr1);
        qb1 = *(const bf16x8*)(qr1 + 32);
        qb2 = *(const bf16x8*)(qr1 + 64);
    }
    const unsigned short* Kb = Kc + (size_t)bh * SEQ * DCAT + (size_t)kh * 512 * DCAT;

    const float rinv0 = rinvbuf[(size_t)bh * SEQ + qrb + c];
    const float rinv1 = rinvbuf[(size_t)bh * SEQ + qrb + 16 + c];

    const int slot8 = (g ^ ((c >> 1) & 3)) * 8;
    const int srow   = lane >> 2;
    const int schunk = (lane & 3) ^ ((lane >> 3) & 3);
    const int ssrcA  = (w * 16 + srow) * DCAT + schunk * 8;
    unsigned short* sdstA = &Ks[w * 512];

    const size_t prow0 = ((size_t)bh * SEQ + qrb + c) * SEQ + kh * 512;
    const size_t prow1 = prow0 + 16 * SEQ;

    #pragma unroll
    for (int p = 0; p < 3; p++) GLDS16(Kb + ssrcA + p * 32, sdstA + p * 2048);
    __builtin_amdgcn_sched_barrier(0);

    for (int t = 0; t < 8; t++) {
        const int buf = t & 1;
        if (t == 0) WAITV("0");
        else        WAITV("8");
        SBARRIER();
        if (t < 7) {
            const unsigned short* src = Kb + (t + 1) * 6144 + ssrcA;
            unsigned short* dst = sdstA + (buf ^ 1) * 6144;
            #pragma unroll
            for (int p = 0; p < 3; p++) GLDS16(src + p * 32, dst + p * 2048);
            __builtin_amdgcn_sched_barrier(0);
        }
        #pragma unroll
        for (int ktl = 0; ktl < 4; ktl++) {
            const int rb = buf * 6144 + (ktl * 16 + c) * 32 + slot8;
            bf16x8 k0 = *(const bf16x8*)&Ks[rb];
            bf16x8 k1 = *(const bf16x8*)&Ks[rb + 2048];
            bf16x8 k2 = *(const bf16x8*)&Ks[rb + 4096];
            f32x4 a0 = __builtin_amdgcn_mfma_f32_16x16x32_bf16(k0, qa0, fzero(), 0, 0, 0);
            f32x4 a1 = __builtin_amdgcn_mfma_f32_16x16x32_bf16(k1, qa1, fzero(), 0, 0, 0);
            f32x4 a2 = __builtin_amdgcn_mfma_f32_16x16x32_bf16(k2, qa2, fzero(), 0, 0, 0);
            f32x4 b0 = __builtin_amdgcn_mfma_f32_16x16x32_bf16(k0, qb0, fzero(), 0, 0, 0);
            f32x4 b1 = __builtin_amdgcn_mfma_f32_16x16x32_bf16(k1, qb1, fzero(), 0, 0, 0);
            f32x4 b2 = __builtin_amdgcn_mfma_f32_16x16x32_bf16(k2, qb2, fzero(), 0, 0, 0);
            f32x4 p0, p1;
            #pragma unroll
            for (int r = 0; r < 4; r++) {
                p0[r] = __expf(a0[r] + a1[r] + a2[r]) * rinv0;
                p1[r] = __expf(b0[r] + b1[r] + b2[r]) * rinv1;
            }
            *(f32x4*)&probs[prow0 + (t * 64 + ktl * 16) + 4 * g] = p0;
            *(f32x4*)&probs[prow1 + (t * 64 + ktl * 16) + 4 * g] = p1;
        }
    }
}

// ---------------- host launch ----------------
extern "C" void kernel_launch(void* const* d_in, const int* in_sizes, int n_in,
                              void* d_out, int out_size, void* d_ws, size_t ws_size,
                              hipStream_t stream)
{
    const float* hs   = (const float*)d_in[0];
    const float* lhs  = (const float*)d_in[1];
    const float* mask = (const float*)d_in[2];
    const float* Wq   = (const float*)d_in[3];
    const float* bq   = (const float*)d_in[4];
    const float* Wk   = (const float*)d_in[5];
    const float* bk   = (const float*)d_in[6];
    const float* Wv   = (const float*)d_in[7];
    const float* bv   = (const float*)d_in[8];
    const float* Wlq  = (const float*)d_in[9];
    const float* blq  = (const float*)d_in[10];
    const float* Wlk  = (const float*)d_in[11];
    const float* blk_ = (const float*)d_in[12];
    const float* Wlv  = (const float*)d_in[13];
    const float* blv  = (const float*)d_in[14];

    float* out   = (float*)d_out;
    float* ctx   = out;
    float* lctx  = out + (size_t)NB * SEQ * 768;
    float* probs = out + (size_t)NB * SEQ * 768 + (size_t)NB * SEQ * 192;

    char* ws = (char*)d_ws;
    unsigned short* Qc     = (unsigned short*)(ws);                 // 18,874,368 B
    unsigned short* Kc     = (unsigned short*)(ws + 18874368);      // 18,874,368 B
    unsigned short* VT     = (unsigned short*)(ws + 37748736);      // 15,728,640 B
    unsigned short* hid16  = (unsigned short*)(ws + 53477376);      // 12,582,912 B
    unsigned short* lay16  = (unsigned short*)(ws + 66060288);      //  3,145,728 B
    unsigned short* wqkv16 = (unsigned short*)(ws + 69206016);      //  3,538,944 B
    unsigned short* wl16   = (unsigned short*)(ws + 72744960);      //    221,184 B
    float*          rinvb  = (float*)(ws + 72966144);               //    393,216 B

    cvt_all<<<dim3(9516), dim3(256), 0, stream>>>(hs, lhs, Wq, Wk, Wv, Wlq, Wlk, Wlv,
                                                  hid16, lay16, wqkv16, wl16);

    proj_gemm<<<dim3(64, 23), dim3(256), 0, stream>>>(hid16, lay16, wqkv16, wl16,
                                                      bq, bk, bv, blq, blk_, blv,
                                                      Qc, Kc, VT);

    pad_fill<<<dim3(384), dim3(256), 0, stream>>>(mask, Qc, Kc);

    attn_a<<<dim3(768), dim3(256), 0, stream>>>(Qc, Kc, VT, ctx, lctx, rinvb);
    attn_b<<<dim3(1536), dim3(256), 0, stream>>>(Qc, Kc, rinvb, probs);
}